// Round 2
// baseline (549.930 us; speedup 1.0000x reference)
//
#include <hip/hip_runtime.h>
#include <hip/hip_bf16.h>

// SlotAttention: B=32, N=16384, D=64, S=7, H=128, 3 iterations.
// Pipeline:
//   proj_kernel      : LN(inputs) -> k = xn@Wk^T, v = xn@Wv^T (bf16, MFMA), stored in ws
//   init_kernel      : slots0 = mu + exp(lsig)*noise, h0, zero accumulators, q0
//   3x { attn_kernel : logits->softmax(+eps)->accumulate W=sum attn*v, C=sum attn (atomics)
//        slot_update : updates=W/C -> GRU(7 steps) -> +MLP -> slots, write d_out,
//                      compute next q, zero W/C }

#define B_ 32
#define N_ 16384
#define D_ 64
#define S_ 7

typedef __bf16 bf16x8 __attribute__((ext_vector_type(8)));
typedef float floatx4 __attribute__((ext_vector_type(4)));

__device__ __forceinline__ unsigned short f2bf(float f) {
  __hip_bfloat16 h = __float2bfloat16(f);
  return __builtin_bit_cast(unsigned short, h);
}
__device__ __forceinline__ float bf2f(unsigned short u) {
  return __uint_as_float(((unsigned int)u) << 16);
}

// ---------------- proj: LN + K/V projection (bf16 MFMA) ----------------
__global__ __launch_bounds__(256) void proj_kernel(
    const float* __restrict__ x,
    const float* __restrict__ lng, const float* __restrict__ lnb,
    const float* __restrict__ Wk, const float* __restrict__ Wv,
    unsigned short* __restrict__ kb, unsigned short* __restrict__ vb)
{
  __shared__ __align__(16) unsigned short s_xn[128 * 64];  // [row][d] bf16
  __shared__ __align__(16) unsigned short s_w[128 * 64];   // [e][d]  bf16 (e<64: Wk, else Wv)
  const int t = threadIdx.x;
  const int lane = t & 63;
  const int w = t >> 6;
  const int R0 = blockIdx.x * 128;

  // stage weights (L2-hot after first blocks)
  for (int i = t; i < 8192; i += 256) {
    int e = i >> 6, d = i & 63;
    float wv = (e < 64) ? Wk[e * 64 + d] : Wv[(e - 64) * 64 + d];
    s_w[i] = f2bf(wv);
  }

  // LayerNorm: wave handles 32 rows, lane = d
  const float gl = lng[lane], bl = lnb[lane];
  for (int i = 0; i < 32; ++i) {
    int r = w * 32 + i;
    float xv = x[(size_t)(R0 + r) * 64 + lane];
    float s1 = xv, s2 = xv * xv;
#pragma unroll
    for (int mm = 1; mm < 64; mm <<= 1) {
      s1 += __shfl_xor(s1, mm);
      s2 += __shfl_xor(s2, mm);
    }
    float mean = s1 * 0.015625f;
    float var = s2 * 0.015625f - mean * mean;
    float rs = rsqrtf(var + 1e-5f);
    s_xn[r * 64 + lane] = f2bf((xv - mean) * rs * gl + bl);
  }
  __syncthreads();

  // MFMA: wave w computes row-tiles {2w, 2w+1} x 8 col-tiles, K=64 (2 steps)
  const int m16 = lane & 15, quad = lane >> 4;
  bf16x8 af[2][2];
#pragma unroll
  for (int rt = 0; rt < 2; ++rt)
#pragma unroll
    for (int kk = 0; kk < 2; ++kk)
      af[rt][kk] = *(const bf16x8*)&s_xn[((w * 2 + rt) * 16 + m16) * 64 + kk * 32 + quad * 8];

  floatx4 acc[2][8];
#pragma unroll
  for (int rt = 0; rt < 2; ++rt)
#pragma unroll
    for (int ct = 0; ct < 8; ++ct)
      acc[rt][ct] = (floatx4){0.f, 0.f, 0.f, 0.f};

#pragma unroll
  for (int ct = 0; ct < 8; ++ct) {
    bf16x8 b0 = *(const bf16x8*)&s_w[(ct * 16 + m16) * 64 + quad * 8];
    bf16x8 b1 = *(const bf16x8*)&s_w[(ct * 16 + m16) * 64 + 32 + quad * 8];
#pragma unroll
    for (int rt = 0; rt < 2; ++rt) {
      acc[rt][ct] = __builtin_amdgcn_mfma_f32_16x16x32_bf16(af[rt][0], b0, acc[rt][ct], 0, 0, 0);
      acc[rt][ct] = __builtin_amdgcn_mfma_f32_16x16x32_bf16(af[rt][1], b1, acc[rt][ct], 0, 0, 0);
    }
  }

  // direct bf16 stores (block covers full 128-row span; L2 merges partial lines)
#pragma unroll
  for (int rt = 0; rt < 2; ++rt)
#pragma unroll
    for (int ct = 0; ct < 8; ++ct)
#pragma unroll
      for (int rg = 0; rg < 4; ++rg) {
        int row = (w * 2 + rt) * 16 + quad * 4 + rg;
        int col = ct * 16 + m16;
        unsigned short val = f2bf(acc[rt][ct][rg]);
        if (col < 64) kb[(size_t)(R0 + row) * 64 + col] = val;
        else          vb[(size_t)(R0 + row) * 64 + (col - 64)] = val;
      }
}

// ---------------- shared helper: q = LN(slots; ln_slots) @ Wq^T * scale ----------------
__device__ void q_from_slots(const float* s_slot, float* s_tmp,
                             const float* __restrict__ g, const float* __restrict__ bb,
                             const float* __restrict__ Wq, float* __restrict__ qout,
                             int lane, int w)
{
  for (int ss = 0; ss < 2; ++ss) {
    int srow = ss * 4 + w;
    if (srow < 7) {
      float xv = s_slot[srow * 64 + lane];
      float s1 = xv, s2 = xv * xv;
#pragma unroll
      for (int mm = 1; mm < 64; mm <<= 1) {
        s1 += __shfl_xor(s1, mm);
        s2 += __shfl_xor(s2, mm);
      }
      float mean = s1 * 0.015625f;
      float var = s2 * 0.015625f - mean * mean;
      float rs = rsqrtf(var + 1e-5f);
      s_tmp[w * 64 + lane] = (xv - mean) * rs * g[lane] + bb[lane];
    }
    __syncthreads();
    if (srow < 7) {
      float acc = 0.f;
      const float* wr = Wq + lane * 64;
      const float* xr = s_tmp + w * 64;
      for (int d = 0; d < 64; ++d) acc += xr[d] * wr[d];
      qout[srow * 64 + lane] = acc * 0.125f;  // scale = D^-0.5
    }
    __syncthreads();
  }
}

// ---------------- init: slots0, h0, zero acc, q0 ----------------
__global__ __launch_bounds__(256) void init_kernel(
    const float* __restrict__ mu, const float* __restrict__ lsig,
    const float* __restrict__ nslots, const float* __restrict__ nh,
    const float* __restrict__ ln_s_g, const float* __restrict__ ln_s_b,
    const float* __restrict__ Wq,
    float* __restrict__ qbuf, float* __restrict__ Wacc, float* __restrict__ Cacc,
    float* __restrict__ h0b)
{
  __shared__ float s_slot[448];
  __shared__ float s_tmp[256];
  const int b = blockIdx.x, t = threadIdx.x, lane = t & 63, w = t >> 6;
  // NOTE: block = 256 threads but 448 slot elements -> strided loops (round-1 bug fix)
  for (int o = t; o < 448; o += 256) {
    int d = o & 63;
    s_slot[o] = mu[d] + expf(lsig[d]) * nslots[b * 448 + o];
    Wacc[b * 448 + o] = 0.f;
  }
  if (t < 64) h0b[b * 64 + t] = mu[t] + expf(lsig[t]) * nh[b * 64 + t];
  if (t < 8) Cacc[b * 8 + t] = 0.f;
  __syncthreads();
  q_from_slots(s_slot, s_tmp, ln_s_g, ln_s_b, Wq, qbuf + b * 448, lane, w);
}

// ---------------- attention pass: accumulate W = sum attn'*v, C = sum attn' ----------------
__global__ __launch_bounds__(256) void attn_kernel(
    const unsigned short* __restrict__ kb, const unsigned short* __restrict__ vb,
    const float* __restrict__ qbuf,
    float* __restrict__ Wacc, float* __restrict__ Cacc)
{
  __shared__ __align__(16) unsigned short s_k[4][64 * 64];  // per-wave k tile (xor-swizzled)
  __shared__ __align__(16) float s_attn[4][64 * 12];        // per-wave attn rows (pad to 12)
  __shared__ __align__(16) float s_red[4][7 * 64];
  __shared__ float s_cred[4][8];
  __shared__ __align__(16) float s_q[448];

  const int b = blockIdx.y;
  const int t = threadIdx.x, lane = t & 63, w = t >> 6;

  for (int i = t; i < 448; i += 256) s_q[i] = qbuf[b * 448 + i];

  float accs[7], cloc[7];
#pragma unroll
  for (int s = 0; s < 7; ++s) { accs[s] = 0.f; cloc[s] = 0.f; }

  const int rowbase = b * N_ + blockIdx.x * 1024 + w * 256;

  for (int tile = 0; tile < 4; ++tile) {
    const int r0 = rowbase + tile * 64;
    // stage k: 16B chunks, xor-swizzle slot = chunk ^ (row&7)
#pragma unroll
    for (int i = 0; i < 8; ++i) {
      int rr = i * 8 + (lane >> 3);
      int cs = lane & 7;
      int gc = cs ^ (rr & 7);
      uint4 d4 = *(const uint4*)&kb[(size_t)(r0 + rr) * 64 + gc * 8];
      *(uint4*)&s_k[w][rr * 64 + cs * 8] = d4;
    }
    __syncthreads();
    // phase 1: lane = row; logits over 7 slots, softmax, +eps
    float lg[7];
#pragma unroll
    for (int s = 0; s < 7; ++s) lg[s] = 0.f;
#pragma unroll
    for (int c = 0; c < 8; ++c) {
      int slot = c ^ (lane & 7);
      uint4 kk = *(const uint4*)&s_k[w][lane * 64 + slot * 8];
      float kf[8];
      kf[0] = __uint_as_float(kk.x << 16);
      kf[1] = __uint_as_float(kk.x & 0xffff0000u);
      kf[2] = __uint_as_float(kk.y << 16);
      kf[3] = __uint_as_float(kk.y & 0xffff0000u);
      kf[4] = __uint_as_float(kk.z << 16);
      kf[5] = __uint_as_float(kk.z & 0xffff0000u);
      kf[6] = __uint_as_float(kk.w << 16);
      kf[7] = __uint_as_float(kk.w & 0xffff0000u);
#pragma unroll
      for (int s = 0; s < 7; ++s) {
        const float* qp = s_q + s * 64 + c * 8;  // broadcast LDS reads
        float a = lg[s];
#pragma unroll
        for (int j = 0; j < 8; ++j) a += kf[j] * qp[j];
        lg[s] = a;
      }
    }
    float mx = lg[0];
#pragma unroll
    for (int s = 1; s < 7; ++s) mx = fmaxf(mx, lg[s]);
    float ex[7]; float sum = 0.f;
#pragma unroll
    for (int s = 0; s < 7; ++s) { ex[s] = __expf(lg[s] - mx); sum += ex[s]; }
    float inv = 1.f / sum;
#pragma unroll
    for (int s = 0; s < 7; ++s) {
      float a = ex[s] * inv + 1e-8f;
      cloc[s] += a;
      s_attn[w][lane * 12 + s] = a;
    }
    s_attn[w][lane * 12 + 7] = 0.f;
    __syncthreads();
    // phase 2: lane = d; rank-64 accumulate
    for (int r = 0; r < 64; ++r) {
      float vv = bf2f(vb[(size_t)(r0 + r) * 64 + lane]);
      float4 a0 = *(const float4*)&s_attn[w][r * 12];
      float4 a1 = *(const float4*)&s_attn[w][r * 12 + 4];
      accs[0] += a0.x * vv; accs[1] += a0.y * vv; accs[2] += a0.z * vv; accs[3] += a0.w * vv;
      accs[4] += a1.x * vv; accs[5] += a1.y * vv; accs[6] += a1.z * vv;
    }
    __syncthreads();
  }
  // reduce cloc across lanes
#pragma unroll
  for (int s = 0; s < 7; ++s) {
    float c = cloc[s];
#pragma unroll
    for (int mm = 1; mm < 64; mm <<= 1) c += __shfl_xor(c, mm);
    cloc[s] = c;
  }
  if (lane == 0) {
#pragma unroll
    for (int s = 0; s < 7; ++s) s_cred[w][s] = cloc[s];
  }
#pragma unroll
  for (int s = 0; s < 7; ++s) s_red[w][s * 64 + lane] = accs[s];
  __syncthreads();
  if (w == 0) {
#pragma unroll
    for (int s = 0; s < 7; ++s) {
      float v = s_red[0][s * 64 + lane] + s_red[1][s * 64 + lane] +
                s_red[2][s * 64 + lane] + s_red[3][s * 64 + lane];
      atomicAdd(&Wacc[b * 448 + s * 64 + lane], v);
    }
    if (lane < 7) {
      float c = s_cred[0][lane] + s_cred[1][lane] + s_cred[2][lane] + s_cred[3][lane];
      atomicAdd(&Cacc[b * 8 + lane], c);
    }
  }
}

// ---------------- slot update: updates=W/C -> GRU -> MLP -> slots; next q; zero acc ----------------
__global__ __launch_bounds__(256) void slot_update_kernel(
    float* __restrict__ Wacc, float* __restrict__ Cacc,
    const float* __restrict__ h0b,
    const float* __restrict__ w_ih, const float* __restrict__ w_hh,
    const float* __restrict__ b_ih, const float* __restrict__ b_hh,
    const float* __restrict__ ln_m_g, const float* __restrict__ ln_m_b,
    const float* __restrict__ w1, const float* __restrict__ b1,
    const float* __restrict__ w2, const float* __restrict__ b2,
    const float* __restrict__ ln_s_g, const float* __restrict__ ln_s_b,
    const float* __restrict__ Wq,
    float* __restrict__ qbuf, float* __restrict__ out)
{
  const int b = blockIdx.x, t = threadIdx.x, lane = t & 63, w = t >> 6;
  __shared__ float s_upd[448];
  __shared__ float s_gi[1344];   // later reused as sn(448) | hid(896)
  __shared__ float s_h[64];
  __shared__ float s_gh[192];
  __shared__ float s_slot[448];
  __shared__ float s_tmp[256];

  // 1. updates = W / C  (strided: 448 > 256 threads — round-1 bug fix)
  for (int o = t; o < 448; o += 256) {
    int s = o >> 6;
    s_upd[o] = Wacc[b * 448 + o] / Cacc[b * 8 + s];
  }
  __syncthreads();
  // 2. gi for all (s, j): gi = updates @ w_ih^T + b_ih
  for (int o = t; o < 1344; o += 256) {
    int s = o / 192, j = o - s * 192;
    float acc = b_ih[j];
    const float* wr = w_ih + j * 64;
    const float* ur = s_upd + s * 64;
    for (int d = 0; d < 64; ++d) acc += ur[d] * wr[d];
    s_gi[o] = acc;
  }
  if (t < 64) s_h[t] = h0b[b * 64 + t];
  __syncthreads();
  // 3. GRU over slot axis (gate order r,z,n; torch semantics)
  for (int s = 0; s < 7; ++s) {
    if (t < 192) {
      float acc = b_hh[t];
      const float* wr = w_hh + t * 64;
      for (int d = 0; d < 64; ++d) acc += s_h[d] * wr[d];
      s_gh[t] = acc;
    }
    __syncthreads();
    if (t < 64) {
      float ir = s_gi[s * 192 + t], iz = s_gi[s * 192 + 64 + t], inn = s_gi[s * 192 + 128 + t];
      float hr = s_gh[t], hz = s_gh[64 + t], hn = s_gh[128 + t];
      float r = 1.f / (1.f + expf(-(ir + hr)));
      float z = 1.f / (1.f + expf(-(iz + hz)));
      float n = tanhf(inn + r * hn);
      float hnew = (1.f - z) * n + z * s_h[t];
      s_slot[s * 64 + t] = hnew;
      s_h[t] = hnew;
    }
    __syncthreads();
  }
  // 4. MLP with residual: slots += relu(LN(slots)@w1^T + b1)@w2^T + b2
  float* s_sn = s_gi;
  float* s_hid = s_gi + 448;
  for (int ss = 0; ss < 2; ++ss) {
    int srow = ss * 4 + w;
    if (srow < 7) {
      float xv = s_slot[srow * 64 + lane];
      float s1 = xv, s2 = xv * xv;
#pragma unroll
      for (int mm = 1; mm < 64; mm <<= 1) {
        s1 += __shfl_xor(s1, mm);
        s2 += __shfl_xor(s2, mm);
      }
      float mean = s1 * 0.015625f;
      float var = s2 * 0.015625f - mean * mean;
      float rs = rsqrtf(var + 1e-5f);
      s_sn[srow * 64 + lane] = (xv - mean) * rs * ln_m_g[lane] + ln_m_b[lane];
    }
  }
  __syncthreads();
  for (int o = t; o < 896; o += 256) {
    int s = o >> 7, hh = o & 127;
    float acc = b1[hh];
    const float* wr = w1 + hh * 64;
    const float* xr = s_sn + s * 64;
    for (int d = 0; d < 64; ++d) acc += xr[d] * wr[d];
    s_hid[o] = fmaxf(acc, 0.f);
  }
  __syncthreads();
  for (int o = t; o < 448; o += 256) {
    int s = o >> 6, d = o & 63;
    float acc = b2[d];
    const float* wr = w2 + d * 128;
    const float* hr = s_hid + s * 128;
    for (int h = 0; h < 128; ++h) acc += hr[h] * wr[h];
    float val = s_slot[o] + acc;
    s_slot[o] = val;
    out[b * 448 + o] = val;
  }
  // 5. zero accumulators for next iteration (strided — round-1 bug fix)
  for (int o = t; o < 448; o += 256) Wacc[b * 448 + o] = 0.f;
  if (t < 8) Cacc[b * 8 + t] = 0.f;
  __syncthreads();
  // 6. q for next iteration from new slots
  q_from_slots(s_slot, s_tmp, ln_s_g, ln_s_b, Wq, qbuf + b * 448, lane, w);
}

extern "C" void kernel_launch(void* const* d_in, const int* in_sizes, int n_in,
                              void* d_out, int out_size, void* d_ws, size_t ws_size,
                              hipStream_t stream)
{
  (void)in_sizes; (void)n_in; (void)out_size; (void)ws_size;
  const float* x      = (const float*)d_in[0];
  const float* ln_in_g = (const float*)d_in[1];
  const float* ln_in_b = (const float*)d_in[2];
  const float* ln_s_g  = (const float*)d_in[3];
  const float* ln_s_b  = (const float*)d_in[4];
  const float* ln_m_g  = (const float*)d_in[5];
  const float* ln_m_b  = (const float*)d_in[6];
  const float* Wq = (const float*)d_in[7];
  const float* Wk = (const float*)d_in[8];
  const float* Wv = (const float*)d_in[9];
  const float* mu = (const float*)d_in[10];
  const float* lsig = (const float*)d_in[11];
  const float* w_ih = (const float*)d_in[12];
  const float* w_hh = (const float*)d_in[13];
  const float* b_ih = (const float*)d_in[14];
  const float* b_hh = (const float*)d_in[15];
  const float* w1 = (const float*)d_in[16];
  const float* b1 = (const float*)d_in[17];
  const float* w2 = (const float*)d_in[18];
  const float* b2 = (const float*)d_in[19];
  const float* nslots = (const float*)d_in[20];
  const float* nh = (const float*)d_in[21];
  // d_in[22] = num_iterations = 3 (fixed by setup; loop count hardcoded)

  // workspace carve: kb/vb bf16 (67.1 MB each), then f32 scratch (~121 KB)
  unsigned short* kb = (unsigned short*)d_ws;
  unsigned short* vb = kb + (size_t)B_ * N_ * D_;
  float* fb = (float*)(vb + (size_t)B_ * N_ * D_);
  float* qbuf = fb;            // 32*448
  float* Wacc = fb + 14336;    // 32*448
  float* Cacc = fb + 28672;    // 32*8
  float* h0b  = fb + 28928;    // 32*64
  float* out = (float*)d_out;

  proj_kernel<<<4096, 256, 0, stream>>>(x, ln_in_g, ln_in_b, Wk, Wv, kb, vb);
  init_kernel<<<32, 256, 0, stream>>>(mu, lsig, nslots, nh, ln_s_g, ln_s_b, Wq,
                                      qbuf, Wacc, Cacc, h0b);
  for (int it = 0; it < 3; ++it) {
    attn_kernel<<<dim3(16, 32), 256, 0, stream>>>(kb, vb, qbuf, Wacc, Cacc);
    slot_update_kernel<<<32, 256, 0, stream>>>(Wacc, Cacc, h0b, w_ih, w_hh, b_ih, b_hh,
                                               ln_m_g, ln_m_b, w1, b1, w2, b2,
                                               ln_s_g, ln_s_b, Wq, qbuf, out);
  }
}